// Round 2
// baseline (209.749 us; speedup 1.0000x reference)
//
#include <hip/hip_runtime.h>

#define HW 4096

// ---------------- fold BN into pointwise conv weights ----------------
// W0T[k*128+o] = w_pw0[o][k] * s1[k];  b0[o] = sum_k w_pw0[o][k] * t1[k]
__global__ __launch_bounds__(256) void fold_kernel(
    const float* __restrict__ g1, const float* __restrict__ be1,
    const float* __restrict__ m1, const float* __restrict__ v1,
    const float* __restrict__ w0,
    const float* __restrict__ g2, const float* __restrict__ be2,
    const float* __restrict__ m2, const float* __restrict__ v2,
    const float* __restrict__ w1,
    float* __restrict__ W0T, float* __restrict__ b0,
    float* __restrict__ W1T, float* __restrict__ b1)
{
  __shared__ float sc[2][128], sh[2][128];
  const int t = threadIdx.x;
  const int half = t >> 7, c = t & 127;
  const float* g  = half ? g2 : g1;
  const float* be = half ? be2 : be1;
  const float* mm = half ? m2 : m1;
  const float* vv = half ? v2 : v1;
  float s = g[c] / sqrtf(vv[c] + 1e-5f);
  sc[half][c] = s;
  sh[half][c] = be[c] - mm[c] * s;
  __syncthreads();
  const int o = c;
  const float* wsrc = half ? w1 : w0;
  float* wd  = half ? W1T : W0T;
  float* bd  = half ? b1 : b0;
  float acc = 0.f;
  for (int k = 0; k < 128; ++k) {
    float wv = wsrc[o * 128 + k];
    wd[k * 128 + o] = wv * sc[half][k];
    acc = fmaf(wv, sh[half][k], acc);
  }
  bd[o] = acc;
}

// ---- out[b][o][hw] = sum_c WT[c][o] * act[b][c][hw] + bias[o]  (all f32) ----
__global__ __launch_bounds__(256) void gemm_wx(
    const float* __restrict__ act, const float* __restrict__ WT,
    const float* __restrict__ bias, float* __restrict__ out)
{
  __shared__ __align__(16) float Wt[64][64];   // [kc][m]
  __shared__ __align__(16) float Bt[64][64];   // [kc][n]
  const int t = threadIdx.x;
  const int nBase = blockIdx.x << 6;
  const int mBase = blockIdx.y << 6;
  const size_t base = (size_t)blockIdx.z * (128 * HW);
  const int tx = t & 15, ty = t >> 4;
  const int n0 = tx << 2, m0 = ty << 2;
  float acc[4][4] = {};

  for (int kc = 0; kc < 2; ++kc) {
    const int kBase = kc << 6;
    for (int idx = t; idx < 64 * 16; idx += 256) {
      const int kr = idx >> 4, jd = idx & 15;
      *(float4*)&Wt[kr][jd << 2] =
          *(const float4*)&WT[(size_t)(kBase + kr) * 128 + mBase + (jd << 2)];
    }
    for (int idx = t; idx < 64 * 16; idx += 256) {
      const int kr = idx >> 4, jd = idx & 15;
      *(float4*)&Bt[kr][jd << 2] =
          *(const float4*)&act[base + (size_t)(kBase + kr) * HW + nBase + (jd << 2)];
    }
    __syncthreads();
    #pragma unroll 8
    for (int k = 0; k < 64; ++k) {
      const float4 av = *(const float4*)&Wt[k][m0];
      const float4 bv = *(const float4*)&Bt[k][n0];
      acc[0][0] = fmaf(av.x, bv.x, acc[0][0]);
      acc[0][1] = fmaf(av.x, bv.y, acc[0][1]);
      acc[0][2] = fmaf(av.x, bv.z, acc[0][2]);
      acc[0][3] = fmaf(av.x, bv.w, acc[0][3]);
      acc[1][0] = fmaf(av.y, bv.x, acc[1][0]);
      acc[1][1] = fmaf(av.y, bv.y, acc[1][1]);
      acc[1][2] = fmaf(av.y, bv.z, acc[1][2]);
      acc[1][3] = fmaf(av.y, bv.w, acc[1][3]);
      acc[2][0] = fmaf(av.z, bv.x, acc[2][0]);
      acc[2][1] = fmaf(av.z, bv.y, acc[2][1]);
      acc[2][2] = fmaf(av.z, bv.z, acc[2][2]);
      acc[2][3] = fmaf(av.z, bv.w, acc[2][3]);
      acc[3][0] = fmaf(av.w, bv.x, acc[3][0]);
      acc[3][1] = fmaf(av.w, bv.y, acc[3][1]);
      acc[3][2] = fmaf(av.w, bv.z, acc[3][2]);
      acc[3][3] = fmaf(av.w, bv.w, acc[3][3]);
    }
    __syncthreads();
  }
  #pragma unroll
  for (int i = 0; i < 4; ++i) {
    const float bs = bias[mBase + m0 + i];
    float4 r;
    r.x = acc[i][0] + bs; r.y = acc[i][1] + bs;
    r.z = acc[i][2] + bs; r.w = acc[i][3] + bs;
    *(float4*)&out[base + (size_t)(mBase + m0 + i) * HW + nBase + n0] = r;
  }
}

// ---- value/om: out[r][g] = sum_k A[r][k]*B[k][g] + bias[g]  (A 32768x128) ----
// blockIdx.x: 0,1 -> value cols 0..127; 2 -> om cols 0..31
__global__ __launch_bounds__(256) void gemm_valom(
    const float* __restrict__ A, const float* __restrict__ wvp,
    const float* __restrict__ bvp, const float* __restrict__ womW,
    const float* __restrict__ bom,
    float* __restrict__ value, float* __restrict__ om)
{
  __shared__ __align__(16) float At[64][68];   // [m][k-chunk], +4 pad
  __shared__ __align__(16) float Bt[64][64];   // [k-chunk][n]
  const int t = threadIdx.x;
  const int nT = blockIdx.x;
  const int rBase = blockIdx.y << 6;
  const int nBase = nT << 6;
  const int tx = t & 15, ty = t >> 4;
  const int n0 = tx << 2, m0 = ty << 2;
  float acc[4][4] = {};

  for (int kc = 0; kc < 2; ++kc) {
    const int kBase = kc << 6;
    for (int idx = t; idx < 64 * 16; idx += 256) {
      const int i = idx >> 4, jd = idx & 15;
      *(float4*)&At[i][jd << 2] =
          *(const float4*)&A[(size_t)(rBase + i) * 128 + kBase + (jd << 2)];
    }
    for (int idx = t; idx < 64 * 16; idx += 256) {
      const int kr = idx >> 4, jd = idx & 15;
      const int n = jd << 2, g = nBase + n;
      float4 f = {0.f, 0.f, 0.f, 0.f};
      if (g < 128)      f = *(const float4*)&wvp[(size_t)(kBase + kr) * 128 + g];
      else if (g < 160) f = *(const float4*)&womW[(size_t)(kBase + kr) * 32 + (g - 128)];
      *(float4*)&Bt[kr][n] = f;
    }
    __syncthreads();
    #pragma unroll 4
    for (int kk = 0; kk < 16; ++kk) {
      float a[4][4];
      #pragma unroll
      for (int i = 0; i < 4; ++i) {
        const float4 f = *(const float4*)&At[m0 + i][kk << 2];
        a[i][0] = f.x; a[i][1] = f.y; a[i][2] = f.z; a[i][3] = f.w;
      }
      #pragma unroll
      for (int q = 0; q < 4; ++q) {
        const float4 bv = *(const float4*)&Bt[(kk << 2) + q][n0];
        #pragma unroll
        for (int i = 0; i < 4; ++i) {
          acc[i][0] = fmaf(a[i][q], bv.x, acc[i][0]);
          acc[i][1] = fmaf(a[i][q], bv.y, acc[i][1]);
          acc[i][2] = fmaf(a[i][q], bv.z, acc[i][2]);
          acc[i][3] = fmaf(a[i][q], bv.w, acc[i][3]);
        }
      }
    }
    __syncthreads();
  }

  if (nT < 2) {
    #pragma unroll
    for (int i = 0; i < 4; ++i) {
      float4 r;
      r.x = acc[i][0] + bvp[nBase + n0 + 0];
      r.y = acc[i][1] + bvp[nBase + n0 + 1];
      r.z = acc[i][2] + bvp[nBase + n0 + 2];
      r.w = acc[i][3] + bvp[nBase + n0 + 3];
      *(float4*)&value[(size_t)(rBase + m0 + i) * 128 + nBase + n0] = r;
    }
  } else if (n0 < 32) {
    #pragma unroll
    for (int i = 0; i < 4; ++i) {
      float4 r;
      r.x = acc[i][0] + bom[n0 + 0];
      r.y = acc[i][1] + bom[n0 + 1];
      r.z = acc[i][2] + bom[n0 + 2];
      r.w = acc[i][3] + bom[n0 + 3];
      *(float4*)&om[(size_t)(rBase + m0 + i) * 32 + n0] = r;
    }
  }
}

// ---------------- deformable bilinear sampling (all f32) ----------------
__global__ __launch_bounds__(256) void dcn_sample(
    const float* __restrict__ value, const float* __restrict__ om,
    float* __restrict__ out)
{
  const int t = threadIdx.x;
  const int blk = blockIdx.x;
  const int b = blk & 7;
  const int s = ((blk >> 3) << 3) + (t >> 5);
  const int cg = (t & 31) << 2;
  const int h = s >> 6, w = s & 63;
  const float* vb  = value + (size_t)b * HW * 128;
  const float* omp = om + ((size_t)b * HW + s) * 32;
  const float fw = (float)w, fh = (float)h;
  float4 acc = {0.f, 0.f, 0.f, 0.f};
  #pragma unroll
  for (int k = 0; k < 9; ++k) {
    const float kx = (float)(k % 3 - 1);
    const float ky = (float)(k / 3 - 1);
    const float dx = omp[k * 3 + 0];
    const float dy = omp[k * 3 + 1];
    const float m  = omp[k * 3 + 2];
    const float px = fw + kx + dx;
    const float py = fh + ky + dy;
    const float x0f = floorf(px), y0f = floorf(py);
    const float fx = px - x0f, fy = py - y0f;
    const int ix = (int)x0f, iy = (int)y0f;
    #pragma unroll
    for (int cy = 0; cy < 2; ++cy) {
      const int yi = iy + cy;
      const float wy = cy ? fy : 1.f - fy;
      const float vy = (yi >= 0 && yi < 64) ? 1.f : 0.f;
      const int yc = min(max(yi, 0), 63);
      #pragma unroll
      for (int cx = 0; cx < 2; ++cx) {
        const int xi = ix + cx;
        const float wx = cx ? fx : 1.f - fx;
        const float vx = (xi >= 0 && xi < 64) ? 1.f : 0.f;
        const int xc = min(max(xi, 0), 63);
        const float wgt = wx * wy * vx * vy * m;
        const float4 v = *(const float4*)&vb[(size_t)(yc * 64 + xc) * 128 + cg];
        acc.x = fmaf(wgt, v.x, acc.x);
        acc.y = fmaf(wgt, v.y, acc.y);
        acc.z = fmaf(wgt, v.z, acc.z);
        acc.w = fmaf(wgt, v.w, acc.w);
      }
    }
  }
  *(float4*)&out[((size_t)b * HW + s) * 128 + cg] = acc;
}

// ---- out2[r][g] = sum_k samp[r][k] * w_op[k][g]  (32768x128 @ 128x128) ----
__global__ __launch_bounds__(256) void gemm_op(
    const float* __restrict__ A, const float* __restrict__ wop,
    float* __restrict__ out)
{
  __shared__ __align__(16) float At[64][68];
  __shared__ __align__(16) float Bt[64][64];
  const int t = threadIdx.x;
  const int nBase = blockIdx.x << 6;
  const int rBase = blockIdx.y << 6;
  const int tx = t & 15, ty = t >> 4;
  const int n0 = tx << 2, m0 = ty << 2;
  float acc[4][4] = {};

  for (int kc = 0; kc < 2; ++kc) {
    const int kBase = kc << 6;
    for (int idx = t; idx < 64 * 16; idx += 256) {
      const int i = idx >> 4, jd = idx & 15;
      *(float4*)&At[i][jd << 2] =
          *(const float4*)&A[(size_t)(rBase + i) * 128 + kBase + (jd << 2)];
    }
    for (int idx = t; idx < 64 * 16; idx += 256) {
      const int kr = idx >> 4, jd = idx & 15;
      *(float4*)&Bt[kr][jd << 2] =
          *(const float4*)&wop[(size_t)(kBase + kr) * 128 + nBase + (jd << 2)];
    }
    __syncthreads();
    #pragma unroll 4
    for (int kk = 0; kk < 16; ++kk) {
      float a[4][4];
      #pragma unroll
      for (int i = 0; i < 4; ++i) {
        const float4 f = *(const float4*)&At[m0 + i][kk << 2];
        a[i][0] = f.x; a[i][1] = f.y; a[i][2] = f.z; a[i][3] = f.w;
      }
      #pragma unroll
      for (int q = 0; q < 4; ++q) {
        const float4 bv = *(const float4*)&Bt[(kk << 2) + q][n0];
        #pragma unroll
        for (int i = 0; i < 4; ++i) {
          acc[i][0] = fmaf(a[i][q], bv.x, acc[i][0]);
          acc[i][1] = fmaf(a[i][q], bv.y, acc[i][1]);
          acc[i][2] = fmaf(a[i][q], bv.z, acc[i][2]);
          acc[i][3] = fmaf(a[i][q], bv.w, acc[i][3]);
        }
      }
    }
    __syncthreads();
  }
  #pragma unroll
  for (int i = 0; i < 4; ++i) {
    float4 r;
    r.x = acc[i][0]; r.y = acc[i][1]; r.z = acc[i][2]; r.w = acc[i][3];
    *(float4*)&out[(size_t)(rBase + m0 + i) * 128 + nBase + n0] = r;
  }
}

extern "C" void kernel_launch(void* const* d_in, const int* in_sizes, int n_in,
                              void* d_out, int out_size, void* d_ws, size_t ws_size,
                              hipStream_t stream)
{
  const float* x    = (const float*)d_in[0];
  const float* g1   = (const float*)d_in[1];
  const float* be1  = (const float*)d_in[2];
  const float* m1   = (const float*)d_in[3];
  const float* v1   = (const float*)d_in[4];
  const float* wpw0 = (const float*)d_in[5];
  const float* wvp  = (const float*)d_in[6];
  const float* bvp  = (const float*)d_in[7];
  const float* womW = (const float*)d_in[8];
  const float* bom  = (const float*)d_in[9];
  const float* wop  = (const float*)d_in[10];
  const float* g2   = (const float*)d_in[11];
  const float* be2  = (const float*)d_in[12];
  const float* m2   = (const float*)d_in[13];
  const float* v2   = (const float*)d_in[14];
  const float* wpw1 = (const float*)d_in[15];

  char* ws = (char*)d_ws;
  // Buffer aliasing: y2 dead after gemm_valom -> samp reuses it;
  // value dead after dcn_sample -> out2 reuses it. Total ~38 MB.
  float* y2    = (float*)(ws + 0);          // 16 MB  (b,o,hw) flat == (b,s,k)
  float* samp  = (float*)(ws + 0);          // 16 MB  (b,s,cg)   [aliases y2]
  float* value = (float*)(ws + 16777216);   // 16 MB  (b,s,cg)
  float* out2  = (float*)(ws + 16777216);   // 16 MB  (b,s,g) flat == (b,c,hw) [aliases value]
  float* omb   = (float*)(ws + 33554432);   //  4 MB  (b,s,32)
  float* W0T   = (float*)(ws + 37748736);   // 64 KB  [c][o]
  float* W1T   = (float*)(ws + 37814272);   // 64 KB
  float* b0    = (float*)(ws + 37879808);   // 512 B
  float* b1    = (float*)(ws + 37880320);   // 512 B

  fold_kernel<<<1, 256, 0, stream>>>(g1, be1, m1, v1, wpw0,
                                     g2, be2, m2, v2, wpw1,
                                     W0T, b0, W1T, b1);
  gemm_wx<<<dim3(64, 2, 8), 256, 0, stream>>>(x, W0T, b0, y2);
  gemm_valom<<<dim3(3, 512), 256, 0, stream>>>(y2, wvp, bvp, womW, bom, value, omb);
  dcn_sample<<<dim3(4096), 256, 0, stream>>>(value, omb, samp);
  gemm_op<<<dim3(2, 512), 256, 0, stream>>>(samp, wop, out2);
  gemm_wx<<<dim3(64, 2, 8), 256, 0, stream>>>(out2, W1T, b1, (float*)d_out);
}